// Round 1
// baseline (1783.320 us; speedup 1.0000x reference)
//
#include <hip/hip_runtime.h>
#include <math.h>

#define B_ 16
#define C_ 512
#define T_ 2048
#define K_ 4096
#define M_ (B_*T_)          // 32768 rows
#define MARGIN_ 0.5f

// ---------------------------------------------------------------------------
// Kernel 0: codebook squared norms.  One wave per code, 4 codes per block.
// ---------------------------------------------------------------------------
__global__ __launch_bounds__(256) void cb_norm_kernel(
    const float* __restrict__ cb, float* __restrict__ norms)
{
    int code = blockIdx.x * 4 + (threadIdx.x >> 6);
    int lane = threadIdx.x & 63;
    const float4* row = reinterpret_cast<const float4*>(cb + (size_t)code * C_);
    float s = 0.f;
#pragma unroll
    for (int j = 0; j < 2; ++j) {           // 128 float4 per row, 2 per lane
        float4 v = row[lane + j * 64];
        s += v.x*v.x + v.y*v.y + v.z*v.z + v.w*v.w;
    }
#pragma unroll
    for (int off = 32; off; off >>= 1) s += __shfl_down(s, off);
    if (lane == 0) norms[code] = s;
}

// ---------------------------------------------------------------------------
// Kernel 1: fused score-GEMM + per-row argmin over a K-half.
//   score(m,k) = ||c_k||^2 - 2 * z_m . c_k      (z-norm constant per row)
//   Z is student_out transposed: z[m][c] = student[b][c][t], m = b*T + t
// BM=128 rows, BN=128 codes, BC=16, 256 threads (tx 16 x ty 16), 8x8 per thread.
// Grid: (M/128, 2) -- blockIdx.y selects K-half (2048 codes each).
// ---------------------------------------------------------------------------
__global__ __launch_bounds__(256) void argmin_kernel(
    const float* __restrict__ student,     // (B, C, T)
    const float* __restrict__ cb,          // (K, C)
    const float* __restrict__ cbn,         // (K)
    const int*   __restrict__ codes,       // (B, T) int32
    float* __restrict__ out_val,           // (2, M)
    int*   __restrict__ out_idx)           // (2, M)
{
    __shared__ float As[16][128];
    __shared__ float Bs[16][132];          // +4 pad: store-conflict relief, keeps 16B align

    const int tid = threadIdx.x;
    const int tx  = tid & 15;
    const int ty  = tid >> 4;
    const int m0  = blockIdx.x * 128;
    const int b   = m0 / T_;
    const int t0  = m0 % T_;
    const int half = blockIdx.y;
    const int kbeg = half * (K_ / 2);
    const int kend = kbeg + (K_ / 2);

    float bestv[8];
    int   besti[8];
    int   tcode[8];
#pragma unroll
    for (int i = 0; i < 8; ++i) {
        bestv[i] = INFINITY;
        besti[i] = 0x7fffffff;
        tcode[i] = codes[m0 + ty * 8 + i];
    }

    for (int k0 = kbeg; k0 < kend; k0 += 128) {
        float acc[8][8];
#pragma unroll
        for (int i = 0; i < 8; ++i)
#pragma unroll
            for (int j = 0; j < 8; ++j) acc[i][j] = 0.f;

        for (int c0 = 0; c0 < C_; c0 += 16) {
            // ---- stage As[cc][tt]: 16 c x 128 t, float4 coalesced (t contiguous)
#pragma unroll
            for (int r = 0; r < 2; ++r) {
                int f  = tid + r * 256;
                int cc = f >> 5;               // 0..15
                int t4 = (f & 31) << 2;        // 0..124
                float4 v = *reinterpret_cast<const float4*>(
                    student + ((size_t)(b * C_ + c0 + cc)) * T_ + (t0 + t4));
                *reinterpret_cast<float4*>(&As[cc][t4]) = v;
            }
            // ---- stage Bs[cc][nn]: 128 codes x 16 c (transposed store)
#pragma unroll
            for (int r = 0; r < 2; ++r) {
                int f  = tid + r * 256;
                int nn = f >> 2;               // 0..127
                int q  = (f & 3) << 2;         // 0,4,8,12
                float4 v = *reinterpret_cast<const float4*>(
                    cb + (size_t)(k0 + nn) * C_ + (c0 + q));
                Bs[q + 0][nn] = v.x;
                Bs[q + 1][nn] = v.y;
                Bs[q + 2][nn] = v.z;
                Bs[q + 3][nn] = v.w;
            }
            __syncthreads();
#pragma unroll
            for (int cc = 0; cc < 16; ++cc) {
                float a[8], bb[8];
                *reinterpret_cast<float4*>(&a[0])  = *reinterpret_cast<const float4*>(&As[cc][ty * 8]);
                *reinterpret_cast<float4*>(&a[4])  = *reinterpret_cast<const float4*>(&As[cc][ty * 8 + 4]);
                *reinterpret_cast<float4*>(&bb[0]) = *reinterpret_cast<const float4*>(&Bs[cc][tx * 8]);
                *reinterpret_cast<float4*>(&bb[4]) = *reinterpret_cast<const float4*>(&Bs[cc][tx * 8 + 4]);
#pragma unroll
                for (int i = 0; i < 8; ++i)
#pragma unroll
                    for (int j = 0; j < 8; ++j)
                        acc[i][j] = fmaf(a[i], bb[j], acc[i][j]);
            }
            __syncthreads();
        }

        // ---- fold this 128-code tile into the running per-row argmin
        float cn[8];
#pragma unroll
        for (int j = 0; j < 8; ++j) cn[j] = cbn[k0 + tx * 8 + j];

#pragma unroll
        for (int i = 0; i < 8; ++i) {
            float lv = INFINITY;
            int   li = 0x7fffffff;
#pragma unroll
            for (int j = 0; j < 8; ++j) {
                int   k = k0 + tx * 8 + j;
                float s = fmaf(-2.f, acc[i][j], cn[j]);
                if (k == tcode[i]) s = INFINITY;          // mask teacher code
                if (s < lv || (s == lv && k < li)) { lv = s; li = k; }
            }
            // reduce across the 16 tx lanes (contiguous within the wave)
#pragma unroll
            for (int off = 1; off < 16; off <<= 1) {
                float ov = __shfl_xor(lv, off);
                int   oi = __shfl_xor(li, off);
                if (ov < lv || (ov == lv && oi < li)) { lv = ov; li = oi; }
            }
            if (lv < bestv[i] || (lv == bestv[i] && li < besti[i])) {
                bestv[i] = lv; besti[i] = li;
            }
        }
    }

    if (tx == 0) {
#pragma unroll
        for (int i = 0; i < 8; ++i) {
            int m = m0 + ty * 8 + i;
            out_val[(size_t)half * M_ + m] = bestv[i];
            out_idx[(size_t)half * M_ + m] = besti[i];
        }
    }
}

// ---------------------------------------------------------------------------
// Kernel 2: combine the two K-half argmin candidates.
// ---------------------------------------------------------------------------
__global__ __launch_bounds__(256) void combine_kernel(
    const float* __restrict__ val, const int* __restrict__ idx,
    int* __restrict__ hard)
{
    int m = blockIdx.x * 256 + threadIdx.x;
    float v0 = val[m],      v1 = val[M_ + m];
    int   i0 = idx[m],      i1 = idx[M_ + m];
    hard[m] = (v1 < v0 || (v1 == v0 && i1 < i0)) ? i1 : i0;
}

// ---------------------------------------------------------------------------
// Kernel 3: per-row d_pos/d_neg/loss/indicator + per-block partial sums.
// One thread per row; t contiguous across threads -> coalesced strided reads.
// ---------------------------------------------------------------------------
__global__ __launch_bounds__(256) void loss_kernel(
    const float* __restrict__ student, const float* __restrict__ teacher,
    const float* __restrict__ cb, const int* __restrict__ hard,
    float* __restrict__ partials)              // (gridDim.x, 4)
{
    const int m = blockIdx.x * 256 + threadIdx.x;
    const int b = m / T_;
    const int t = m % T_;
    const float* sp = student + (size_t)b * C_ * T_ + t;
    const float* tp = teacher + (size_t)b * C_ * T_ + t;
    const float4* cp = reinterpret_cast<const float4*>(cb + (size_t)hard[m] * C_);

    float dp = 0.f, dn = 0.f;
    for (int c4 = 0; c4 < C_ / 4; ++c4) {
        float4 cv = cp[c4];
        float a0 = tp[(size_t)(c4 * 4 + 0) * T_];
        float a1 = tp[(size_t)(c4 * 4 + 1) * T_];
        float a2 = tp[(size_t)(c4 * 4 + 2) * T_];
        float a3 = tp[(size_t)(c4 * 4 + 3) * T_];
        float p0 = sp[(size_t)(c4 * 4 + 0) * T_];
        float p1 = sp[(size_t)(c4 * 4 + 1) * T_];
        float p2 = sp[(size_t)(c4 * 4 + 2) * T_];
        float p3 = sp[(size_t)(c4 * 4 + 3) * T_];
        float e;
        e = a0 - p0; dp = fmaf(e, e, dp);
        e = a1 - p1; dp = fmaf(e, e, dp);
        e = a2 - p2; dp = fmaf(e, e, dp);
        e = a3 - p3; dp = fmaf(e, e, dp);
        e = a0 - cv.x; dn = fmaf(e, e, dn);
        e = a1 - cv.y; dn = fmaf(e, e, dn);
        e = a2 - cv.z; dn = fmaf(e, e, dn);
        e = a3 - cv.w; dn = fmaf(e, e, dn);
    }
    float dpos = sqrtf(dp);
    float dneg = sqrtf(dn);
    float loss = fmaxf(dpos - dneg + MARGIN_, 0.f);
    float ind  = (dneg > dpos + MARGIN_) ? 1.f : 0.f;

    // block reduction: wave shuffle then LDS across 4 waves
    __shared__ float sh[4][4];
    float v0 = loss, v1 = dpos, v2 = dneg, v3 = ind;
#pragma unroll
    for (int off = 32; off; off >>= 1) {
        v0 += __shfl_down(v0, off);
        v1 += __shfl_down(v1, off);
        v2 += __shfl_down(v2, off);
        v3 += __shfl_down(v3, off);
    }
    int w = threadIdx.x >> 6, lane = threadIdx.x & 63;
    if (lane == 0) { sh[w][0] = v0; sh[w][1] = v1; sh[w][2] = v2; sh[w][3] = v3; }
    __syncthreads();
    if (threadIdx.x == 0) {
        float s0 = 0, s1 = 0, s2 = 0, s3 = 0;
#pragma unroll
        for (int ww = 0; ww < 4; ++ww) {
            s0 += sh[ww][0]; s1 += sh[ww][1]; s2 += sh[ww][2]; s3 += sh[ww][3];
        }
        partials[blockIdx.x * 4 + 0] = s0;
        partials[blockIdx.x * 4 + 1] = s1;
        partials[blockIdx.x * 4 + 2] = s2;
        partials[blockIdx.x * 4 + 3] = s3;
    }
}

// ---------------------------------------------------------------------------
// Kernel 4: final deterministic reduction of 128 partial rows -> 4 means.
// ---------------------------------------------------------------------------
__global__ __launch_bounds__(128) void final_kernel(
    const float* __restrict__ partials, float* __restrict__ out)
{
    __shared__ float sh[2][4];
    int tid = threadIdx.x;                       // 128 threads, one partial row each
    float s0 = partials[tid * 4 + 0];
    float s1 = partials[tid * 4 + 1];
    float s2 = partials[tid * 4 + 2];
    float s3 = partials[tid * 4 + 3];
#pragma unroll
    for (int off = 32; off; off >>= 1) {
        s0 += __shfl_down(s0, off);
        s1 += __shfl_down(s1, off);
        s2 += __shfl_down(s2, off);
        s3 += __shfl_down(s3, off);
    }
    int w = tid >> 6, lane = tid & 63;
    if (lane == 0) { sh[w][0] = s0; sh[w][1] = s1; sh[w][2] = s2; sh[w][3] = s3; }
    __syncthreads();
    if (tid == 0) {
        const float inv = 1.0f / (float)M_;
        out[0] = (sh[0][0] + sh[1][0]) * inv;    // loss mean
        out[1] = (sh[0][1] + sh[1][1]) * inv;    // d_pos mean
        out[2] = (sh[0][2] + sh[1][2]) * inv;    // d_neg mean
        out[3] = (sh[0][3] + sh[1][3]) * inv;    // margin_satisfied mean
    }
}

// ---------------------------------------------------------------------------
extern "C" void kernel_launch(void* const* d_in, const int* in_sizes, int n_in,
                              void* d_out, int out_size, void* d_ws, size_t ws_size,
                              hipStream_t stream)
{
    (void)in_sizes; (void)n_in; (void)out_size; (void)ws_size;
    const float* student = (const float*)d_in[0];
    const float* teacher = (const float*)d_in[1];
    const float* cb      = (const float*)d_in[2];
    const int*   codes   = (const int*)d_in[3];
    float* out = (float*)d_out;

    char* ws = (char*)d_ws;
    float* cbn   = (float*)(ws);                       // 16 KB  (4096 f32)
    float* val   = (float*)(ws + (16u  << 10));        // 256 KB (2 x 32768 f32)
    int*   idx   = (int*)  (ws + (272u << 10));        // 256 KB (2 x 32768 i32)
    int*   hard  = (int*)  (ws + (528u << 10));        // 128 KB (32768 i32)
    float* parts = (float*)(ws + (656u << 10));        // 2 KB   (128 x 4 f32)

    cb_norm_kernel<<<K_ / 4, 256, 0, stream>>>(cb, cbn);
    argmin_kernel<<<dim3(M_ / 128, 2), 256, 0, stream>>>(student, cb, cbn, codes, val, idx);
    combine_kernel<<<M_ / 256, 256, 0, stream>>>(val, idx, hard);
    loss_kernel<<<M_ / 256, 256, 0, stream>>>(student, teacher, cb, hard, parts);
    final_kernel<<<1, 128, 0, stream>>>(parts, out);
}

// Round 2
// 588.881 us; speedup vs baseline: 3.0283x; 3.0283x over previous
//
#include <hip/hip_runtime.h>
#include <math.h>

#define B_ 16
#define C_ 512
#define T_ 2048
#define K_ 4096
#define M_ (B_*T_)          // 32768 rows
#define MARGIN_ 0.5f

typedef __bf16          bf16x8 __attribute__((ext_vector_type(8)));
typedef float           f32x4  __attribute__((ext_vector_type(4)));
typedef unsigned short  u16x8  __attribute__((ext_vector_type(8)));
typedef unsigned short  u16x4  __attribute__((ext_vector_type(4)));

static __device__ __forceinline__ unsigned short bf16_bits(__bf16 h) {
    union { __bf16 b; unsigned short u; } cv; cv.b = h; return cv.u;
}

// ===========================================================================
// FAST PATH (MFMA, needs ~74 MB of d_ws)
// ===========================================================================

// ---------------------------------------------------------------------------
// pack_A: student (B,C,T) fp32 -> Apack[M][1024] bf16 (cols 0..511 = hi,
// 512..1023 = lo), m = b*T + t.  64x64 transpose tiles through LDS.
// ---------------------------------------------------------------------------
__global__ __launch_bounds__(256) void packA_kernel(
    const float* __restrict__ student, unsigned short* __restrict__ Apack)
{
    __shared__ float ts[64][65];                 // +1 pad: 2-way max on col reads
    const int tid = threadIdx.x;
    const int t0 = blockIdx.x * 64;
    const int c0 = blockIdx.y * 64;
    const int b  = blockIdx.z;

#pragma unroll
    for (int r = 0; r < 4; ++r) {
        int f  = tid + r * 256;
        int i  = f >> 4;                          // c row 0..63
        int j4 = (f & 15) << 2;                   // t col 0..60
        float4 v = *reinterpret_cast<const float4*>(
            student + ((size_t)(b * C_ + c0 + i)) * T_ + (t0 + j4));
        *reinterpret_cast<float4*>(&ts[i][j4]) = v;
    }
    __syncthreads();

#pragma unroll
    for (int r = 0; r < 2; ++r) {
        int f  = tid + r * 256;                   // 0..511
        int j  = f >> 3;                          // t row 0..63
        int pi = f & 7;                           // 8-elem piece in c
        u16x8 hv, lv;
#pragma unroll
        for (int u = 0; u < 8; ++u) {
            float x = ts[pi * 8 + u][j];
            __bf16 h = (__bf16)x;
            __bf16 l = (__bf16)(x - (float)h);
            hv[u] = bf16_bits(h);
            lv[u] = bf16_bits(l);
        }
        size_t row = (size_t)(b * T_ + t0 + j) * 1024;
        *reinterpret_cast<u16x8*>(Apack + row + c0 + pi * 8)       = hv;
        *reinterpret_cast<u16x8*>(Apack + row + 512 + c0 + pi * 8) = lv;
    }
}

// ---------------------------------------------------------------------------
// pack_B + codebook norms: codebook (K,C) fp32 -> Bpack[K][1024] (hi|lo),
// cbn[k] = ||c_k||^2 (fp32).  One wave per code row.
// ---------------------------------------------------------------------------
__global__ __launch_bounds__(256) void packB_norm_kernel(
    const float* __restrict__ cb, unsigned short* __restrict__ Bpack,
    float* __restrict__ cbn)
{
    int code = blockIdx.x * 4 + (threadIdx.x >> 6);
    int lane = threadIdx.x & 63;
    const float* row = cb + (size_t)code * C_;
    unsigned short* orow = Bpack + (size_t)code * 1024;

    float s = 0.f;
#pragma unroll
    for (int half = 0; half < 2; ++half) {
        int c = half * 256 + lane * 4;
        float4 v = *reinterpret_cast<const float4*>(row + c);
        s += v.x*v.x + v.y*v.y + v.z*v.z + v.w*v.w;
        u16x4 hv, lv;
        float xs[4] = {v.x, v.y, v.z, v.w};
#pragma unroll
        for (int u = 0; u < 4; ++u) {
            __bf16 h = (__bf16)xs[u];
            __bf16 l = (__bf16)(xs[u] - (float)h);
            hv[u] = bf16_bits(h);
            lv[u] = bf16_bits(l);
        }
        *reinterpret_cast<u16x4*>(orow + c)       = hv;
        *reinterpret_cast<u16x4*>(orow + 512 + c) = lv;
    }
#pragma unroll
    for (int off = 32; off; off >>= 1) s += __shfl_down(s, off);
    if (lane == 0) cbn[code] = s;
}

// ---------------------------------------------------------------------------
// MFMA score-GEMM + fused per-row argmin.
//   dot(z,c) ~= zh.ch + zl.ch + zh.cl   (3 bf16 MFMA passes)
//   score    =  ||c||^2 - 2*dot        (row-constant ||z||^2 dropped)
// Block: 128 m-rows x 128 codes, 4 waves (2m x 2n), 16x16x32 MFMA, BK=32.
// Grid: (M/128, 4) -- blockIdx.y = K-quarter (1024 codes, 8 code-tiles).
// Candidate streams: quarter*2 + wn  (each wave-column reduces 64 codes/tile).
// LDS XOR piece-swizzle: slot = p ^ ((row>>1)&3)  -> worst 2-way (free, m136).
// ---------------------------------------------------------------------------
__global__ __launch_bounds__(256) void mfma_argmin_kernel(
    const unsigned short* __restrict__ Apack,
    const unsigned short* __restrict__ Bpack,
    const float* __restrict__ cbn, const int* __restrict__ codes,
    float* __restrict__ out_val, int* __restrict__ out_idx)
{
    __shared__ unsigned short tiles[4][128][32];  // 0=Azh 1=Azl 2=Bch 3=Bcl, 32 KB

    const int tid = threadIdx.x;
    const int m0  = blockIdx.x * 128;
    const int q   = blockIdx.y;
    const int l   = tid & 63;
    const int wv  = tid >> 6;
    const int wm  = wv >> 1, wn = wv & 1;
    const int lr  = l & 15;                        // frag row/col lane
    const int lk  = l >> 4;                        // k-piece lane

    // teacher codes for this lane's 16 output rows
    int tc[16];
#pragma unroll
    for (int i = 0; i < 4; ++i)
#pragma unroll
        for (int r = 0; r < 4; ++r)
            tc[i * 4 + r] = codes[m0 + wm * 64 + i * 16 + lk * 4 + r];

    float bestv[16];
    int   besti[16];
#pragma unroll
    for (int e = 0; e < 16; ++e) { bestv[e] = INFINITY; besti[e] = 0x7fffffff; }

    for (int ct = 0; ct < 8; ++ct) {
        const int kbase = q * 1024 + ct * 128;
        f32x4 acc[4][4];
#pragma unroll
        for (int i = 0; i < 4; ++i)
#pragma unroll
            for (int j = 0; j < 4; ++j) acc[i][j] = (f32x4)0.f;

        for (int c0 = 0; c0 < C_; c0 += 32) {
            // ---- stage zh,zl,ch,cl 128x32 tiles (reg-staged, swizzled store)
#pragma unroll
            for (int v = 0; v < 2; ++v) {
#pragma unroll
                for (int rr = 0; rr < 2; ++rr) {
                    int f   = tid + rr * 256;
                    int row = f >> 2;
                    int p   = f & 3;
                    int sw  = (p ^ ((row >> 1) & 3)) * 8;
                    u16x8 av = *reinterpret_cast<const u16x8*>(
                        Apack + (size_t)(m0 + row) * 1024 + v * 512 + c0 + p * 8);
                    *reinterpret_cast<u16x8*>(&tiles[v][row][sw]) = av;
                    u16x8 bv = *reinterpret_cast<const u16x8*>(
                        Bpack + (size_t)(kbase + row) * 1024 + v * 512 + c0 + p * 8);
                    *reinterpret_cast<u16x8*>(&tiles[2 + v][row][sw]) = bv;
                }
            }
            __syncthreads();

            bf16x8 azh[4], azl[4], bch[4], bcl[4];
#pragma unroll
            for (int i = 0; i < 4; ++i) {
                int ar  = wm * 64 + i * 16 + lr;
                int asw = (lk ^ ((ar >> 1) & 3)) * 8;
                azh[i] = *reinterpret_cast<const bf16x8*>(&tiles[0][ar][asw]);
                azl[i] = *reinterpret_cast<const bf16x8*>(&tiles[1][ar][asw]);
                int br  = wn * 64 + i * 16 + lr;
                int bsw = (lk ^ ((br >> 1) & 3)) * 8;
                bch[i] = *reinterpret_cast<const bf16x8*>(&tiles[2][br][bsw]);
                bcl[i] = *reinterpret_cast<const bf16x8*>(&tiles[3][br][bsw]);
            }
#pragma unroll
            for (int i = 0; i < 4; ++i)
#pragma unroll
                for (int j = 0; j < 4; ++j) {
                    acc[i][j] = __builtin_amdgcn_mfma_f32_16x16x32_bf16(
                        azh[i], bch[j], acc[i][j], 0, 0, 0);
                    acc[i][j] = __builtin_amdgcn_mfma_f32_16x16x32_bf16(
                        azl[i], bch[j], acc[i][j], 0, 0, 0);
                    acc[i][j] = __builtin_amdgcn_mfma_f32_16x16x32_bf16(
                        azh[i], bcl[j], acc[i][j], 0, 0, 0);
                }
            __syncthreads();
        }

        // ---- fold this 128-code tile into the running argmin
        float cn[4];
#pragma unroll
        for (int j = 0; j < 4; ++j) cn[j] = cbn[kbase + wn * 64 + j * 16 + lr];

#pragma unroll
        for (int i = 0; i < 4; ++i)
#pragma unroll
            for (int r = 0; r < 4; ++r) {
                float lv = INFINITY;
                int   li = 0x7fffffff;
#pragma unroll
                for (int j = 0; j < 4; ++j) {
                    int   k = kbase + wn * 64 + j * 16 + lr;
                    float s = fmaf(-2.f, acc[i][j][r], cn[j]);
                    if (k == tc[i * 4 + r]) s = INFINITY;   // mask teacher code
                    if (s < lv || (s == lv && k < li)) { lv = s; li = k; }
                }
#pragma unroll
                for (int off = 1; off < 16; off <<= 1) {     // reduce 16 lr lanes
                    float ov = __shfl_xor(lv, off);
                    int   oi = __shfl_xor(li, off);
                    if (ov < lv || (ov == lv && oi < li)) { lv = ov; li = oi; }
                }
                int e = i * 4 + r;
                if (lv < bestv[e] || (lv == bestv[e] && li < besti[e])) {
                    bestv[e] = lv; besti[e] = li;
                }
            }
    }

    if (lr == 0) {
        int cand = q * 2 + wn;
#pragma unroll
        for (int i = 0; i < 4; ++i)
#pragma unroll
            for (int r = 0; r < 4; ++r) {
                int m = m0 + wm * 64 + i * 16 + lk * 4 + r;
                out_val[(size_t)cand * M_ + m] = bestv[i * 4 + r];
                out_idx[(size_t)cand * M_ + m] = besti[i * 4 + r];
            }
    }
}

// ---------------------------------------------------------------------------
// combine 8 candidate streams -> hard negative index per row
// ---------------------------------------------------------------------------
__global__ __launch_bounds__(256) void combine8_kernel(
    const float* __restrict__ val, const int* __restrict__ idx,
    int* __restrict__ hard)
{
    int m = blockIdx.x * 256 + threadIdx.x;
    float bv = val[m];
    int   bi = idx[m];
#pragma unroll
    for (int c = 1; c < 8; ++c) {
        float v = val[(size_t)c * M_ + m];
        int   i = idx[(size_t)c * M_ + m];
        if (v < bv || (v == bv && i < bi)) { bv = v; bi = i; }
    }
    hard[m] = bi;
}

// ===========================================================================
// FALLBACK PATH (fp32 VALU, ~658 KB ws) — proven correct in R1
// ===========================================================================

__global__ __launch_bounds__(256) void cb_norm_kernel(
    const float* __restrict__ cb, float* __restrict__ norms)
{
    int code = blockIdx.x * 4 + (threadIdx.x >> 6);
    int lane = threadIdx.x & 63;
    const float4* row = reinterpret_cast<const float4*>(cb + (size_t)code * C_);
    float s = 0.f;
#pragma unroll
    for (int j = 0; j < 2; ++j) {
        float4 v = row[lane + j * 64];
        s += v.x*v.x + v.y*v.y + v.z*v.z + v.w*v.w;
    }
#pragma unroll
    for (int off = 32; off; off >>= 1) s += __shfl_down(s, off);
    if (lane == 0) norms[code] = s;
}

__global__ __launch_bounds__(256) void argmin_kernel(
    const float* __restrict__ student, const float* __restrict__ cb,
    const float* __restrict__ cbn, const int* __restrict__ codes,
    float* __restrict__ out_val, int* __restrict__ out_idx)
{
    __shared__ float As[16][128];
    __shared__ float Bs[16][132];

    const int tid = threadIdx.x;
    const int tx  = tid & 15;
    const int ty  = tid >> 4;
    const int m0  = blockIdx.x * 128;
    const int b   = m0 / T_;
    const int t0  = m0 % T_;
    const int half = blockIdx.y;
    const int kbeg = half * (K_ / 2);
    const int kend = kbeg + (K_ / 2);

    float bestv[8];
    int   besti[8];
    int   tcode[8];
#pragma unroll
    for (int i = 0; i < 8; ++i) {
        bestv[i] = INFINITY;
        besti[i] = 0x7fffffff;
        tcode[i] = codes[m0 + ty * 8 + i];
    }

    for (int k0 = kbeg; k0 < kend; k0 += 128) {
        float acc[8][8];
#pragma unroll
        for (int i = 0; i < 8; ++i)
#pragma unroll
            for (int j = 0; j < 8; ++j) acc[i][j] = 0.f;

        for (int c0 = 0; c0 < C_; c0 += 16) {
#pragma unroll
            for (int r = 0; r < 2; ++r) {
                int f  = tid + r * 256;
                int cc = f >> 5;
                int t4 = (f & 31) << 2;
                float4 v = *reinterpret_cast<const float4*>(
                    student + ((size_t)(b * C_ + c0 + cc)) * T_ + (t0 + t4));
                *reinterpret_cast<float4*>(&As[cc][t4]) = v;
            }
#pragma unroll
            for (int r = 0; r < 2; ++r) {
                int f  = tid + r * 256;
                int nn = f >> 2;
                int qq = (f & 3) << 2;
                float4 v = *reinterpret_cast<const float4*>(
                    cb + (size_t)(k0 + nn) * C_ + (c0 + qq));
                Bs[qq + 0][nn] = v.x;
                Bs[qq + 1][nn] = v.y;
                Bs[qq + 2][nn] = v.z;
                Bs[qq + 3][nn] = v.w;
            }
            __syncthreads();
#pragma unroll
            for (int cc = 0; cc < 16; ++cc) {
                float a[8], bb[8];
                *reinterpret_cast<float4*>(&a[0])  = *reinterpret_cast<const float4*>(&As[cc][ty * 8]);
                *reinterpret_cast<float4*>(&a[4])  = *reinterpret_cast<const float4*>(&As[cc][ty * 8 + 4]);
                *reinterpret_cast<float4*>(&bb[0]) = *reinterpret_cast<const float4*>(&Bs[cc][tx * 8]);
                *reinterpret_cast<float4*>(&bb[4]) = *reinterpret_cast<const float4*>(&Bs[cc][tx * 8 + 4]);
#pragma unroll
                for (int i = 0; i < 8; ++i)
#pragma unroll
                    for (int j = 0; j < 8; ++j)
                        acc[i][j] = fmaf(a[i], bb[j], acc[i][j]);
            }
            __syncthreads();
        }

        float cn[8];
#pragma unroll
        for (int j = 0; j < 8; ++j) cn[j] = cbn[k0 + tx * 8 + j];

#pragma unroll
        for (int i = 0; i < 8; ++i) {
            float lv = INFINITY;
            int   li = 0x7fffffff;
#pragma unroll
            for (int j = 0; j < 8; ++j) {
                int   k = k0 + tx * 8 + j;
                float s = fmaf(-2.f, acc[i][j], cn[j]);
                if (k == tcode[i]) s = INFINITY;
                if (s < lv || (s == lv && k < li)) { lv = s; li = k; }
            }
#pragma unroll
            for (int off = 1; off < 16; off <<= 1) {
                float ov = __shfl_xor(lv, off);
                int   oi = __shfl_xor(li, off);
                if (ov < lv || (ov == lv && oi < li)) { lv = ov; li = oi; }
            }
            if (lv < bestv[i] || (lv == bestv[i] && li < besti[i])) {
                bestv[i] = lv; besti[i] = li;
            }
        }
    }

    if (tx == 0) {
#pragma unroll
        for (int i = 0; i < 8; ++i) {
            int m = m0 + ty * 8 + i;
            out_val[(size_t)half * M_ + m] = bestv[i];
            out_idx[(size_t)half * M_ + m] = besti[i];
        }
    }
}

__global__ __launch_bounds__(256) void combine2_kernel(
    const float* __restrict__ val, const int* __restrict__ idx,
    int* __restrict__ hard)
{
    int m = blockIdx.x * 256 + threadIdx.x;
    float v0 = val[m],      v1 = val[M_ + m];
    int   i0 = idx[m],      i1 = idx[M_ + m];
    hard[m] = (v1 < v0 || (v1 == v0 && i1 < i0)) ? i1 : i0;
}

// ===========================================================================
// Shared epilogue: per-row distances + deterministic mean reduction
// ===========================================================================

__global__ __launch_bounds__(256) void loss_kernel(
    const float* __restrict__ student, const float* __restrict__ teacher,
    const float* __restrict__ cb, const int* __restrict__ hard,
    float* __restrict__ partials)
{
    const int m = blockIdx.x * 256 + threadIdx.x;
    const int b = m / T_;
    const int t = m % T_;
    const float* sp = student + (size_t)b * C_ * T_ + t;
    const float* tp = teacher + (size_t)b * C_ * T_ + t;
    const float4* cp = reinterpret_cast<const float4*>(cb + (size_t)hard[m] * C_);

    float dp = 0.f, dn = 0.f;
    for (int c4 = 0; c4 < C_ / 4; ++c4) {
        float4 cv = cp[c4];
        float a0 = tp[(size_t)(c4 * 4 + 0) * T_];
        float a1 = tp[(size_t)(c4 * 4 + 1) * T_];
        float a2 = tp[(size_t)(c4 * 4 + 2) * T_];
        float a3 = tp[(size_t)(c4 * 4 + 3) * T_];
        float p0 = sp[(size_t)(c4 * 4 + 0) * T_];
        float p1 = sp[(size_t)(c4 * 4 + 1) * T_];
        float p2 = sp[(size_t)(c4 * 4 + 2) * T_];
        float p3 = sp[(size_t)(c4 * 4 + 3) * T_];
        float e;
        e = a0 - p0; dp = fmaf(e, e, dp);
        e = a1 - p1; dp = fmaf(e, e, dp);
        e = a2 - p2; dp = fmaf(e, e, dp);
        e = a3 - p3; dp = fmaf(e, e, dp);
        e = a0 - cv.x; dn = fmaf(e, e, dn);
        e = a1 - cv.y; dn = fmaf(e, e, dn);
        e = a2 - cv.z; dn = fmaf(e, e, dn);
        e = a3 - cv.w; dn = fmaf(e, e, dn);
    }
    float dpos = sqrtf(dp);
    float dneg = sqrtf(dn);
    float loss = fmaxf(dpos - dneg + MARGIN_, 0.f);
    float ind  = (dneg > dpos + MARGIN_) ? 1.f : 0.f;

    __shared__ float sh[4][4];
    float v0 = loss, v1 = dpos, v2 = dneg, v3 = ind;
#pragma unroll
    for (int off = 32; off; off >>= 1) {
        v0 += __shfl_down(v0, off);
        v1 += __shfl_down(v1, off);
        v2 += __shfl_down(v2, off);
        v3 += __shfl_down(v3, off);
    }
    int w = threadIdx.x >> 6, lane = threadIdx.x & 63;
    if (lane == 0) { sh[w][0] = v0; sh[w][1] = v1; sh[w][2] = v2; sh[w][3] = v3; }
    __syncthreads();
    if (threadIdx.x == 0) {
        float s0 = 0, s1 = 0, s2 = 0, s3 = 0;
#pragma unroll
        for (int ww = 0; ww < 4; ++ww) {
            s0 += sh[ww][0]; s1 += sh[ww][1]; s2 += sh[ww][2]; s3 += sh[ww][3];
        }
        partials[blockIdx.x * 4 + 0] = s0;
        partials[blockIdx.x * 4 + 1] = s1;
        partials[blockIdx.x * 4 + 2] = s2;
        partials[blockIdx.x * 4 + 3] = s3;
    }
}

__global__ __launch_bounds__(128) void final_kernel(
    const float* __restrict__ partials, float* __restrict__ out)
{
    __shared__ float sh[2][4];
    int tid = threadIdx.x;
    float s0 = partials[tid * 4 + 0];
    float s1 = partials[tid * 4 + 1];
    float s2 = partials[tid * 4 + 2];
    float s3 = partials[tid * 4 + 3];
#pragma unroll
    for (int off = 32; off; off >>= 1) {
        s0 += __shfl_down(s0, off);
        s1 += __shfl_down(s1, off);
        s2 += __shfl_down(s2, off);
        s3 += __shfl_down(s3, off);
    }
    int w = tid >> 6, lane = tid & 63;
    if (lane == 0) { sh[w][0] = s0; sh[w][1] = s1; sh[w][2] = s2; sh[w][3] = s3; }
    __syncthreads();
    if (tid == 0) {
        const float inv = 1.0f / (float)M_;
        out[0] = (sh[0][0] + sh[1][0]) * inv;
        out[1] = (sh[0][1] + sh[1][1]) * inv;
        out[2] = (sh[0][2] + sh[1][2]) * inv;
        out[3] = (sh[0][3] + sh[1][3]) * inv;
    }
}

// ===========================================================================
extern "C" void kernel_launch(void* const* d_in, const int* in_sizes, int n_in,
                              void* d_out, int out_size, void* d_ws, size_t ws_size,
                              hipStream_t stream)
{
    (void)in_sizes; (void)n_in; (void)out_size;
    const float* student = (const float*)d_in[0];
    const float* teacher = (const float*)d_in[1];
    const float* cb      = (const float*)d_in[2];
    const int*   codes   = (const int*)d_in[3];
    float* out = (float*)d_out;
    char* ws = (char*)d_ws;

    // fast-path ws layout
    const size_t OFF_APACK = 0;                       // 64 MB
    const size_t OFF_BPACK = 67108864;                // 8 MB
    const size_t OFF_CBN   = OFF_BPACK + 8388608;     // 16 KB
    const size_t OFF_VAL   = OFF_CBN + 16384;         // 1 MB  (8 x M f32)
    const size_t OFF_IDX   = OFF_VAL + 1048576;       // 1 MB  (8 x M i32)
    const size_t OFF_HARD  = OFF_IDX + 1048576;       // 128 KB
    const size_t OFF_PARTS = OFF_HARD + 131072;       // 2 KB
    const size_t NEED      = OFF_PARTS + 2048;

    if (ws_size >= NEED) {
        unsigned short* Apack = (unsigned short*)(ws + OFF_APACK);
        unsigned short* Bpack = (unsigned short*)(ws + OFF_BPACK);
        float* cbn   = (float*)(ws + OFF_CBN);
        float* val   = (float*)(ws + OFF_VAL);
        int*   idx   = (int*)  (ws + OFF_IDX);
        int*   hard  = (int*)  (ws + OFF_HARD);
        float* parts = (float*)(ws + OFF_PARTS);

        packA_kernel<<<dim3(T_ / 64, C_ / 64, B_), 256, 0, stream>>>(student, Apack);
        packB_norm_kernel<<<K_ / 4, 256, 0, stream>>>(cb, Bpack, cbn);
        mfma_argmin_kernel<<<dim3(M_ / 128, 4), 256, 0, stream>>>(
            Apack, Bpack, cbn, codes, val, idx);
        combine8_kernel<<<M_ / 256, 256, 0, stream>>>(val, idx, hard);
        loss_kernel<<<M_ / 256, 256, 0, stream>>>(student, teacher, cb, hard, parts);
        final_kernel<<<1, 128, 0, stream>>>(parts, out);
    } else {
        float* cbn   = (float*)(ws);
        float* val   = (float*)(ws + (16u  << 10));
        int*   idx   = (int*)  (ws + (272u << 10));
        int*   hard  = (int*)  (ws + (528u << 10));
        float* parts = (float*)(ws + (656u << 10));

        cb_norm_kernel<<<K_ / 4, 256, 0, stream>>>(cb, cbn);
        argmin_kernel<<<dim3(M_ / 128, 2), 256, 0, stream>>>(student, cb, cbn, codes, val, idx);
        combine2_kernel<<<M_ / 256, 256, 0, stream>>>(val, idx, hard);
        loss_kernel<<<M_ / 256, 256, 0, stream>>>(student, teacher, cb, hard, parts);
        final_kernel<<<1, 128, 0, stream>>>(parts, out);
    }
}

// Round 3
// 279.323 us; speedup vs baseline: 6.3844x; 2.1082x over previous
//
#include <hip/hip_runtime.h>
#include <math.h>

#define B_ 16
#define C_ 512
#define T_ 2048
#define K_ 4096
#define M_ (B_*T_)          // 32768 rows
#define MARGIN_ 0.5f

typedef __bf16          bf16x8 __attribute__((ext_vector_type(8)));
typedef float           f32x4  __attribute__((ext_vector_type(4)));
typedef unsigned short  u16x8  __attribute__((ext_vector_type(8)));

static __device__ __forceinline__ unsigned short bf16_bits(__bf16 h) {
    union { __bf16 b; unsigned short u; } cv; cv.b = h; return cv.u;
}
static __device__ __forceinline__ unsigned int umin_(unsigned int a, unsigned int b) {
    return a < b ? a : b;
}
static __device__ __forceinline__ unsigned int umax_(unsigned int a, unsigned int b) {
    return a > b ? a : b;
}
// async global->LDS, 16B per lane. LDS dest = wave-uniform base + lane*16.
static __device__ __forceinline__ void gload_lds16(const void* g, void* l) {
    __builtin_amdgcn_global_load_lds(
        (const __attribute__((address_space(1))) unsigned int*)g,
        (__attribute__((address_space(3))) unsigned int*)l,
        16, 0, 0);
}

// ---------------------------------------------------------------------------
// pack_A: student (B,C,T) fp32 -> Apack[M][512] bf16 (hi only), m = b*T + t.
// 64x64 transpose tiles through LDS.
// ---------------------------------------------------------------------------
__global__ __launch_bounds__(256) void packA_kernel(
    const float* __restrict__ student, unsigned short* __restrict__ Apack)
{
    __shared__ float ts[64][65];
    const int tid = threadIdx.x;
    const int t0 = blockIdx.x * 64;
    const int c0 = blockIdx.y * 64;
    const int b  = blockIdx.z;

#pragma unroll
    for (int r = 0; r < 4; ++r) {
        int f  = tid + r * 256;
        int i  = f >> 4;                          // c row 0..63
        int j4 = (f & 15) << 2;                   // t col 0..60
        float4 v = *reinterpret_cast<const float4*>(
            student + ((size_t)(b * C_ + c0 + i)) * T_ + (t0 + j4));
        *reinterpret_cast<float4*>(&ts[i][j4]) = v;
    }
    __syncthreads();

#pragma unroll
    for (int r = 0; r < 2; ++r) {
        int f  = tid + r * 256;                   // 0..511
        int j  = f >> 3;                          // t row 0..63
        int pi = f & 7;                           // 8-elem piece in c
        u16x8 hv;
#pragma unroll
        for (int u = 0; u < 8; ++u) {
            float x = ts[pi * 8 + u][j];
            hv[u] = bf16_bits((__bf16)x);
        }
        *reinterpret_cast<u16x8*>(
            Apack + (size_t)(b * T_ + t0 + j) * 512 + c0 + pi * 8) = hv;
    }
}

// ---------------------------------------------------------------------------
// pack_B + biased norms: codebook (K,C) fp32 -> Bpack[K][512] bf16 (hi),
// cbnb[k] = ||c_k||^2 + 1024 (keeps packed scores positive).
// ---------------------------------------------------------------------------
__global__ __launch_bounds__(256) void packB_norm_kernel(
    const float* __restrict__ cb, unsigned short* __restrict__ Bpack,
    float* __restrict__ cbnb)
{
    int code = blockIdx.x * 4 + (threadIdx.x >> 6);
    int lane = threadIdx.x & 63;
    const float* row = cb + (size_t)code * C_;
    unsigned short* orow = Bpack + (size_t)code * 512;

    float s = 0.f;
#pragma unroll
    for (int half = 0; half < 2; ++half) {
        int c = half * 256 + lane * 4;
        float4 v = *reinterpret_cast<const float4*>(row + c);
        s += v.x*v.x + v.y*v.y + v.z*v.z + v.w*v.w;
        unsigned short h0 = bf16_bits((__bf16)v.x);
        unsigned short h1 = bf16_bits((__bf16)v.y);
        unsigned short h2 = bf16_bits((__bf16)v.z);
        unsigned short h3 = bf16_bits((__bf16)v.w);
        ushort4 hv = make_ushort4(h0, h1, h2, h3);
        *reinterpret_cast<ushort4*>(orow + c) = hv;
    }
#pragma unroll
    for (int off = 32; off; off >>= 1) s += __shfl_down(s, off);
    if (lane == 0) cbnb[code] = s + 1024.0f;
}

// ---------------------------------------------------------------------------
// 1-pass bf16 MFMA screen + fused per-row packed top-2.
//   score'(m,k) = ||c_k||^2 + 1024 - 2*(zh . ch)    (row-const ||z||^2 dropped)
//   packed      = ((uint)(score' * 256) << 12) | k   (20-bit quant, 12-bit idx)
// Block: 128 m-rows x 128 codes, 4 waves (2m x 2n), 16x16x32 MFMA, BK=64.
// Grid: (M/128, 4); stream id = quarter*2 + wn. No teacher-mask here (done
// at exact rescore). LDS: linear global_load_lds dest + XOR slot swizzle
// slot = piece ^ (row&7)  (conflict-free on ds_read_b128, verified pattern).
// ---------------------------------------------------------------------------
__global__ __launch_bounds__(256) void screen_kernel(
    const unsigned short* __restrict__ Apack,
    const unsigned short* __restrict__ Bpack,
    const float* __restrict__ cbnb,
    uint2* __restrict__ out2)                      // [8 streams][M]
{
    __shared__ unsigned short tiles[2][128][64];   // A, B; 32 KB

    const int tid = threadIdx.x;
    const int l   = tid & 63;
    const int wv  = tid >> 6;
    const int wm  = wv >> 1, wn = wv & 1;
    const int lr  = l & 15;
    const int lk  = l >> 4;
    const int m0  = blockIdx.x * 128;
    const int q   = blockIdx.y;

    // staging: lane l of a chunk covers row = chunk*8 + (l>>3), lds piece l&7;
    // global piece pre-unswizzled: p_g = (l&7) ^ (l>>3).  Row stride 1024 B.
    const int laneg = (l >> 3) * 1024 + (((l & 7) ^ (l >> 3)) * 16);

    unsigned int u1[16], u2v[16];
#pragma unroll
    for (int e = 0; e < 16; ++e) { u1[e] = 0xFFFFFFFFu; u2v[e] = 0xFFFFFFFFu; }

    const char* Abase = (const char*)Apack + (size_t)m0 * 1024 + laneg;

    for (int ct = 0; ct < 8; ++ct) {
        const int kbase = q * 1024 + ct * 128;
        const char* Bbase = (const char*)Bpack + (size_t)kbase * 1024 + laneg;

        f32x4 acc[4][4];
#pragma unroll
        for (int i = 0; i < 4; ++i)
#pragma unroll
            for (int j = 0; j < 4; ++j) acc[i][j] = (f32x4)0.f;

        for (int c0 = 0; c0 < C_; c0 += 64) {
            __syncthreads();                      // previous step's readers done
#pragma unroll
            for (int r = 0; r < 4; ++r) {
                int chunk = wv * 4 + r;           // 0..15 (8 rows / chunk)
                gload_lds16(Abase + (size_t)chunk * 8192 + c0 * 2,
                            &tiles[0][chunk * 8][0]);
                gload_lds16(Bbase + (size_t)chunk * 8192 + c0 * 2,
                            &tiles[1][chunk * 8][0]);
            }
            __syncthreads();                      // drains vmcnt -> loads landed

#pragma unroll
            for (int kk = 0; kk < 2; ++kk) {
                bf16x8 a[4], bb[4];
#pragma unroll
                for (int i = 0; i < 4; ++i) {
                    int ar = wm * 64 + i * 16 + lr;
                    int as = ((kk * 4 + lk) ^ (ar & 7)) * 8;
                    a[i] = *reinterpret_cast<const bf16x8*>(&tiles[0][ar][as]);
                    int br = wn * 64 + i * 16 + lr;
                    int bs = ((kk * 4 + lk) ^ (br & 7)) * 8;
                    bb[i] = *reinterpret_cast<const bf16x8*>(&tiles[1][br][bs]);
                }
#pragma unroll
                for (int i = 0; i < 4; ++i)
#pragma unroll
                    for (int j = 0; j < 4; ++j)
                        acc[i][j] = __builtin_amdgcn_mfma_f32_16x16x32_bf16(
                            a[i], bb[j], acc[i][j], 0, 0, 0);
            }
        }

        // ---- fold this 128-code tile into running packed top-2 (per lane)
#pragma unroll
        for (int j = 0; j < 4; ++j) {
            int k = kbase + wn * 64 + j * 16 + lr;
            float cnb = cbnb[k];
#pragma unroll
            for (int i = 0; i < 4; ++i)
#pragma unroll
                for (int r = 0; r < 4; ++r) {
                    float s = fmaf(-2.f, acc[i][j][r], cnb);
                    s = fmaxf(s, 0.f);
                    unsigned int u = ((unsigned int)(s * 256.0f) << 12)
                                     | (unsigned int)k;
                    int e = i * 4 + r;
                    bool lt = u < u1[e];
                    unsigned int mn2 = umin_(u2v[e], u);
                    u2v[e] = lt ? u1[e] : mn2;
                    u1[e]  = umin_(u1[e], u);
                }
        }
    }

    // ---- one cross-lane top-2 merge over the 16 lr lanes
#pragma unroll
    for (int e = 0; e < 16; ++e) {
        unsigned int a1 = u1[e], a2 = u2v[e];
#pragma unroll
        for (int off = 1; off < 16; off <<= 1) {
            unsigned int b1 = (unsigned int)__shfl_xor((int)a1, off);
            unsigned int b2 = (unsigned int)__shfl_xor((int)a2, off);
            unsigned int m1 = umin_(a1, b1);
            a2 = umin_(umax_(a1, b1), umin_(a2, b2));
            a1 = m1;
        }
        u1[e] = a1; u2v[e] = a2;
    }

    if (lr == 0) {
        int cand = q * 2 + wn;
#pragma unroll
        for (int i = 0; i < 4; ++i)
#pragma unroll
            for (int r = 0; r < 4; ++r) {
                int m = m0 + wm * 64 + i * 16 + lk * 4 + r;
                out2[(size_t)cand * M_ + m] = make_uint2(u1[i * 4 + r], u2v[i * 4 + r]);
            }
    }
}

// ---------------------------------------------------------------------------
// combine 8 candidate streams -> global packed top-2 per row
// ---------------------------------------------------------------------------
__global__ __launch_bounds__(256) void combine8_kernel(
    const uint2* __restrict__ out2, uint2* __restrict__ hard2)
{
    int m = blockIdx.x * 256 + threadIdx.x;
    uint2 g = out2[m];
#pragma unroll
    for (int c = 1; c < 8; ++c) {
        uint2 o = out2[(size_t)c * M_ + m];
        unsigned int m1 = umin_(g.x, o.x);
        g.y = umin_(umax_(g.x, o.x), umin_(g.y, o.y));
        g.x = m1;
    }
    hard2[m] = g;
}

// ---------------------------------------------------------------------------
// fused exact rescore + loss. For each row: exact fp32 student-distance of
// both candidates picks the index (teacher-code masked, tie -> smaller k);
// d_neg = ||teacher - codebook[chosen]||, d_pos = ||teacher - student||.
// Deterministic two-stage mean reduction.
// ---------------------------------------------------------------------------
__global__ __launch_bounds__(256) void loss_kernel(
    const float* __restrict__ student, const float* __restrict__ teacher,
    const float* __restrict__ cb, const uint2* __restrict__ hard2,
    const int* __restrict__ codes, float* __restrict__ partials)
{
    const int m = blockIdx.x * 256 + threadIdx.x;
    const int b = m / T_;
    const int t = m % T_;
    uint2 h = hard2[m];
    const int k1 = (int)(h.x & 0xFFFu);
    const int k2 = (int)(h.y & 0xFFFu);
    const int tc = codes[m];

    const float* sp = student + (size_t)b * C_ * T_ + t;
    const float* tp = teacher + (size_t)b * C_ * T_ + t;
    const float4* c1p = reinterpret_cast<const float4*>(cb + (size_t)k1 * C_);
    const float4* c2p = reinterpret_cast<const float4*>(cb + (size_t)k2 * C_);

    float dp = 0.f, ds1 = 0.f, ds2 = 0.f, dt1 = 0.f, dt2 = 0.f;
    for (int c4 = 0; c4 < C_ / 4; ++c4) {
        float4 cv1 = c1p[c4];
        float4 cv2 = c2p[c4];
        float a0 = tp[(size_t)(c4 * 4 + 0) * T_];
        float a1 = tp[(size_t)(c4 * 4 + 1) * T_];
        float a2 = tp[(size_t)(c4 * 4 + 2) * T_];
        float a3 = tp[(size_t)(c4 * 4 + 3) * T_];
        float p0 = sp[(size_t)(c4 * 4 + 0) * T_];
        float p1 = sp[(size_t)(c4 * 4 + 1) * T_];
        float p2 = sp[(size_t)(c4 * 4 + 2) * T_];
        float p3 = sp[(size_t)(c4 * 4 + 3) * T_];
        float e;
        e = a0 - p0;   dp  = fmaf(e, e, dp);
        e = a1 - p1;   dp  = fmaf(e, e, dp);
        e = a2 - p2;   dp  = fmaf(e, e, dp);
        e = a3 - p3;   dp  = fmaf(e, e, dp);
        e = p0 - cv1.x; ds1 = fmaf(e, e, ds1);
        e = p1 - cv1.y; ds1 = fmaf(e, e, ds1);
        e = p2 - cv1.z; ds1 = fmaf(e, e, ds1);
        e = p3 - cv1.w; ds1 = fmaf(e, e, ds1);
        e = p0 - cv2.x; ds2 = fmaf(e, e, ds2);
        e = p1 - cv2.y; ds2 = fmaf(e, e, ds2);
        e = p2 - cv2.z; ds2 = fmaf(e, e, ds2);
        e = p3 - cv2.w; ds2 = fmaf(e, e, ds2);
        e = a0 - cv1.x; dt1 = fmaf(e, e, dt1);
        e = a1 - cv1.y; dt1 = fmaf(e, e, dt1);
        e = a2 - cv1.z; dt1 = fmaf(e, e, dt1);
        e = a3 - cv1.w; dt1 = fmaf(e, e, dt1);
        e = a0 - cv2.x; dt2 = fmaf(e, e, dt2);
        e = a1 - cv2.y; dt2 = fmaf(e, e, dt2);
        e = a2 - cv2.z; dt2 = fmaf(e, e, dt2);
        e = a3 - cv2.w; dt2 = fmaf(e, e, dt2);
    }

    bool v1 = (k1 != tc), v2 = (k2 != tc);
    bool take2;
    if (!v1)      take2 = true;
    else if (!v2) take2 = false;
    else          take2 = (ds2 < ds1) || (ds2 == ds1 && k2 < k1);
    float dn = take2 ? dt2 : dt1;

    float dpos = sqrtf(dp);
    float dneg = sqrtf(dn);
    float loss = fmaxf(dpos - dneg + MARGIN_, 0.f);
    float ind  = (dneg > dpos + MARGIN_) ? 1.f : 0.f;

    __shared__ float sh[4][4];
    float v0 = loss, vv1 = dpos, vv2 = dneg, vv3 = ind;
#pragma unroll
    for (int off = 32; off; off >>= 1) {
        v0  += __shfl_down(v0, off);
        vv1 += __shfl_down(vv1, off);
        vv2 += __shfl_down(vv2, off);
        vv3 += __shfl_down(vv3, off);
    }
    int w = threadIdx.x >> 6, lane = threadIdx.x & 63;
    if (lane == 0) { sh[w][0] = v0; sh[w][1] = vv1; sh[w][2] = vv2; sh[w][3] = vv3; }
    __syncthreads();
    if (threadIdx.x == 0) {
        float s0 = 0, s1 = 0, s2 = 0, s3 = 0;
#pragma unroll
        for (int ww = 0; ww < 4; ++ww) {
            s0 += sh[ww][0]; s1 += sh[ww][1]; s2 += sh[ww][2]; s3 += sh[ww][3];
        }
        partials[blockIdx.x * 4 + 0] = s0;
        partials[blockIdx.x * 4 + 1] = s1;
        partials[blockIdx.x * 4 + 2] = s2;
        partials[blockIdx.x * 4 + 3] = s3;
    }
}

// ---------------------------------------------------------------------------
// final deterministic reduction of 128 partial rows -> 4 means.
// ---------------------------------------------------------------------------
__global__ __launch_bounds__(128) void final_kernel(
    const float* __restrict__ partials, float* __restrict__ out)
{
    __shared__ float sh[2][4];
    int tid = threadIdx.x;
    float s0 = partials[tid * 4 + 0];
    float s1 = partials[tid * 4 + 1];
    float s2 = partials[tid * 4 + 2];
    float s3 = partials[tid * 4 + 3];
#pragma unroll
    for (int off = 32; off; off >>= 1) {
        s0 += __shfl_down(s0, off);
        s1 += __shfl_down(s1, off);
        s2 += __shfl_down(s2, off);
        s3 += __shfl_down(s3, off);
    }
    int w = tid >> 6, lane = tid & 63;
    if (lane == 0) { sh[w][0] = s0; sh[w][1] = s1; sh[w][2] = s2; sh[w][3] = s3; }
    __syncthreads();
    if (tid == 0) {
        const float inv = 1.0f / (float)M_;
        out[0] = (sh[0][0] + sh[1][0]) * inv;
        out[1] = (sh[0][1] + sh[1][1]) * inv;
        out[2] = (sh[0][2] + sh[1][2]) * inv;
        out[3] = (sh[0][3] + sh[1][3]) * inv;
    }
}

// ===========================================================================
extern "C" void kernel_launch(void* const* d_in, const int* in_sizes, int n_in,
                              void* d_out, int out_size, void* d_ws, size_t ws_size,
                              hipStream_t stream)
{
    (void)in_sizes; (void)n_in; (void)out_size; (void)ws_size;
    const float* student = (const float*)d_in[0];
    const float* teacher = (const float*)d_in[1];
    const float* cb      = (const float*)d_in[2];
    const int*   codes   = (const int*)d_in[3];
    float* out = (float*)d_out;
    char* ws = (char*)d_ws;

    // ws layout (~36 MB; harness provides >= 74 MB per R2 fast path)
    const size_t OFF_APACK = 0;                        // 32 MB (M x 512 u16)
    const size_t OFF_BPACK = (size_t)M_ * 512 * 2;     //  4 MB (K x 512 u16)
    const size_t OFF_CBN   = OFF_BPACK + (size_t)K_ * 512 * 2;   // 16 KB
    const size_t OFF_OUT2  = OFF_CBN + K_ * 4;         //  2 MB (8 x M uint2)
    const size_t OFF_HARD  = OFF_OUT2 + (size_t)8 * M_ * 8;      // 256 KB
    const size_t OFF_PARTS = OFF_HARD + (size_t)M_ * 8;          // 2 KB

    unsigned short* Apack = (unsigned short*)(ws + OFF_APACK);
    unsigned short* Bpack = (unsigned short*)(ws + OFF_BPACK);
    float* cbnb  = (float*)(ws + OFF_CBN);
    uint2* out2  = (uint2*)(ws + OFF_OUT2);
    uint2* hard2 = (uint2*)(ws + OFF_HARD);
    float* parts = (float*)(ws + OFF_PARTS);

    packA_kernel<<<dim3(T_ / 64, C_ / 64, B_), 256, 0, stream>>>(student, Apack);
    packB_norm_kernel<<<K_ / 4, 256, 0, stream>>>(cb, Bpack, cbnb);
    screen_kernel<<<dim3(M_ / 128, 4), 256, 0, stream>>>(Apack, Bpack, cbnb, out2);
    combine8_kernel<<<M_ / 256, 256, 0, stream>>>(out2, hard2);
    loss_kernel<<<M_ / 256, 256, 0, stream>>>(student, teacher, cb, hard2, codes, parts);
    final_kernel<<<1, 128, 0, stream>>>(parts, out);
}

// Round 4
// 274.769 us; speedup vs baseline: 6.4903x; 1.0166x over previous
//
#include <hip/hip_runtime.h>
#include <math.h>

#define B_ 16
#define C_ 512
#define T_ 2048
#define K_ 4096
#define M_ (B_*T_)          // 32768 rows
#define MARGIN_ 0.5f

typedef __bf16          bf16x8 __attribute__((ext_vector_type(8)));
typedef float           f32x4  __attribute__((ext_vector_type(4)));
typedef unsigned short  u16x8  __attribute__((ext_vector_type(8)));

static __device__ __forceinline__ unsigned short bf16_bits(__bf16 h) {
    union { __bf16 b; unsigned short u; } cv; cv.b = h; return cv.u;
}
static __device__ __forceinline__ unsigned int umin_(unsigned int a, unsigned int b) {
    return a < b ? a : b;
}
static __device__ __forceinline__ unsigned int umax_(unsigned int a, unsigned int b) {
    return a > b ? a : b;
}
// async global->LDS, 16B per lane. LDS dest = wave-uniform base + lane*16.
static __device__ __forceinline__ void gload_lds16(const void* g, void* l) {
    __builtin_amdgcn_global_load_lds(
        (const __attribute__((address_space(1))) unsigned int*)g,
        (__attribute__((address_space(3))) unsigned int*)l,
        16, 0, 0);
}

// ---------------------------------------------------------------------------
// pack_A: student (B,C,T) fp32 -> Apack[M][512] bf16, m = b*T + t.
// 64x64 transpose tiles through LDS.
// ---------------------------------------------------------------------------
__global__ __launch_bounds__(256) void packA_kernel(
    const float* __restrict__ student, unsigned short* __restrict__ Apack)
{
    __shared__ float ts[64][65];
    const int tid = threadIdx.x;
    const int t0 = blockIdx.x * 64;
    const int c0 = blockIdx.y * 64;
    const int b  = blockIdx.z;

#pragma unroll
    for (int r = 0; r < 4; ++r) {
        int f  = tid + r * 256;
        int i  = f >> 4;                          // c row 0..63
        int j4 = (f & 15) << 2;                   // t col 0..60
        float4 v = *reinterpret_cast<const float4*>(
            student + ((size_t)(b * C_ + c0 + i)) * T_ + (t0 + j4));
        *reinterpret_cast<float4*>(&ts[i][j4]) = v;
    }
    __syncthreads();

#pragma unroll
    for (int r = 0; r < 2; ++r) {
        int f  = tid + r * 256;                   // 0..511
        int j  = f >> 3;                          // t row 0..63
        int pi = f & 7;                           // 8-elem piece in c
        u16x8 hv;
#pragma unroll
        for (int u = 0; u < 8; ++u) {
            float x = ts[pi * 8 + u][j];
            hv[u] = bf16_bits((__bf16)x);
        }
        *reinterpret_cast<u16x8*>(
            Apack + (size_t)(b * T_ + t0 + j) * 512 + c0 + pi * 8) = hv;
    }
}

// ---------------------------------------------------------------------------
// pack_B + scaled-biased norms: codebook (K,C) fp32 -> Bpack[K][512] bf16,
// cbnb256[k] = (||c_k||^2 + 1024) * 256   (pre-scaled for packed quantize).
// ---------------------------------------------------------------------------
__global__ __launch_bounds__(256) void packB_norm_kernel(
    const float* __restrict__ cb, unsigned short* __restrict__ Bpack,
    float* __restrict__ cbnb256)
{
    int code = blockIdx.x * 4 + (threadIdx.x >> 6);
    int lane = threadIdx.x & 63;
    const float* row = cb + (size_t)code * C_;
    unsigned short* orow = Bpack + (size_t)code * 512;

    float s = 0.f;
#pragma unroll
    for (int half = 0; half < 2; ++half) {
        int c = half * 256 + lane * 4;
        float4 v = *reinterpret_cast<const float4*>(row + c);
        s += v.x*v.x + v.y*v.y + v.z*v.z + v.w*v.w;
        ushort4 hv = make_ushort4(bf16_bits((__bf16)v.x), bf16_bits((__bf16)v.y),
                                  bf16_bits((__bf16)v.z), bf16_bits((__bf16)v.w));
        *reinterpret_cast<ushort4*>(orow + c) = hv;
    }
#pragma unroll
    for (int off = 32; off; off >>= 1) s += __shfl_down(s, off);
    if (lane == 0) cbnb256[code] = (s + 1024.0f) * 256.0f;
}

// ---------------------------------------------------------------------------
// 1-pass bf16 MFMA screen + fused per-row packed top-2, 2-phase LDS pipeline.
//   score256(m,k) = (||c_k||^2 + 1024)*256 - 512*(zh . ch)
//   packed        = ((uint)score256 << 12) | k    (20-bit quant, 12-bit idx)
// Block: 128 m-rows x 128 codes, 4 waves (2m x 2n), 16x16x32 MFMA, BK=64.
// Grid: (M/128, 4); stream id = quarter*2 + wn.
// LDS: DOUBLE-buffered linear global_load_lds dest + XOR piece swizzle
// (slot = piece ^ (row&7)); stage(s+1) issued before compute(s); the
// __syncthreads at step end drains vmcnt -> T3-minimum 2-phase pipeline.
// ---------------------------------------------------------------------------
__global__ __launch_bounds__(256) void screen_kernel(
    const unsigned short* __restrict__ Apack,
    const unsigned short* __restrict__ Bpack,
    const float* __restrict__ cbnb256,
    uint2* __restrict__ out2)                      // [8 streams][M]
{
    __shared__ unsigned short tiles[2][2][128][64];   // [buf][A/B], 64 KB

    const int tid = threadIdx.x;
    const int l   = tid & 63;
    const int wv  = tid >> 6;
    const int wm  = wv >> 1, wn = wv & 1;
    const int lr  = l & 15;
    const int lk  = l >> 4;
    const int m0  = blockIdx.x * 128;
    const int q   = blockIdx.y;

    // staging: lane l covers LDS row chunk*8 + (l>>3), lds piece l&7;
    // global piece pre-unswizzled: p_g = (l&7) ^ (l>>3). Row stride 1024 B.
    const int laneg = (l >> 3) * 1024 + (((l & 7) ^ (l >> 3)) * 16);
    const char* Abase  = (const char*)Apack + (size_t)m0 * 1024 + laneg;
    const char* Bbase0 = (const char*)Bpack + (size_t)q * 1048576 + laneg;

    unsigned int u1[16], u2v[16];
#pragma unroll
    for (int e = 0; e < 16; ++e) { u1[e] = 0xFFFFFFFFu; u2v[e] = 0xFFFFFFFFu; }

    f32x4 acc[4][4];
#pragma unroll
    for (int i = 0; i < 4; ++i)
#pragma unroll
        for (int j = 0; j < 4; ++j) acc[i][j] = (f32x4)0.f;

    auto stage_step = [&](int ct, int cc, int buf) {
        const char* Bb = Bbase0 + (size_t)ct * 131072;     // 128 rows x 1024 B
        const int cb = cc * 128;                           // byte offset in row
#pragma unroll
        for (int r2 = 0; r2 < 4; ++r2) {
            int chunk = wv * 4 + r2;                       // 0..15, 8 rows each
            gload_lds16(Abase + (size_t)chunk * 8192 + cb,
                        &tiles[buf][0][chunk * 8][0]);
            gload_lds16(Bb + (size_t)chunk * 8192 + cb,
                        &tiles[buf][1][chunk * 8][0]);
        }
    };

    auto compute_step = [&](int buf) {
#pragma unroll
        for (int kk = 0; kk < 2; ++kk) {
            bf16x8 a[4], bb[4];
#pragma unroll
            for (int i = 0; i < 4; ++i) {
                int ar = wm * 64 + i * 16 + lr;
                int as = ((kk * 4 + lk) ^ (ar & 7)) * 8;
                a[i] = *reinterpret_cast<const bf16x8*>(&tiles[buf][0][ar][as]);
                int br = wn * 64 + i * 16 + lr;
                int bs = ((kk * 4 + lk) ^ (br & 7)) * 8;
                bb[i] = *reinterpret_cast<const bf16x8*>(&tiles[buf][1][br][bs]);
            }
#pragma unroll
            for (int i = 0; i < 4; ++i)
#pragma unroll
                for (int j = 0; j < 4; ++j)
                    acc[i][j] = __builtin_amdgcn_mfma_f32_16x16x32_bf16(
                        a[i], bb[j], acc[i][j], 0, 0, 0);
        }
    };

    auto fold = [&](int ct) {
        const int kbase = q * 1024 + ct * 128;
        unsigned int kk4[4];
        float cnb[4];
#pragma unroll
        for (int j = 0; j < 4; ++j) {
            int k = kbase + wn * 64 + j * 16 + lr;
            kk4[j] = (unsigned int)k;
            cnb[j] = cbnb256[k];
        }
#pragma unroll
        for (int i = 0; i < 4; ++i)
#pragma unroll
            for (int r = 0; r < 4; ++r) {
                int e = i * 4 + r;
                unsigned int p[4];
#pragma unroll
                for (int j = 0; j < 4; ++j) {
                    float s = fmaf(-512.f, acc[i][j][r], cnb[j]);
                    s = fmaxf(s, 0.f);
                    p[j] = ((unsigned int)s << 12) | kk4[j];
                }
                // exact top-2 insert of sorted pairs (min3 pattern)
                unsigned int mn0 = umin_(p[0], p[1]), mx0 = umax_(p[0], p[1]);
                unsigned int mn1 = umin_(p[2], p[3]), mx1 = umax_(p[2], p[3]);
                unsigned int t0 = umax_(u1[e], mn0);
                u1[e]  = umin_(u1[e], mn0);
                u2v[e] = umin_(umin_(t0, u2v[e]), mx0);
                unsigned int t1 = umax_(u1[e], mn1);
                u1[e]  = umin_(u1[e], mn1);
                u2v[e] = umin_(umin_(t1, u2v[e]), mx1);
            }
        // re-zero acc for next code-tile
#pragma unroll
        for (int i = 0; i < 4; ++i)
#pragma unroll
            for (int j = 0; j < 4; ++j) acc[i][j] = (f32x4)0.f;
    };

    // ---- 2-phase pipelined main loop: 8 code-tiles x 8 C-steps
    stage_step(0, 0, 0);
    __syncthreads();
    for (int ct = 0; ct < 8; ++ct) {
#pragma unroll
        for (int cc = 0; cc < 8; ++cc) {
            const int buf = cc & 1;
            if (cc < 7)      stage_step(ct, cc + 1, buf ^ 1);
            else if (ct < 7) stage_step(ct + 1, 0, buf ^ 1);
            compute_step(buf);
            if (cc == 7) fold(ct);
            __syncthreads();     // implicit vmcnt(0): next-step loads landed
        }
    }

    // ---- one cross-lane top-2 merge over the 16 lr lanes
#pragma unroll
    for (int e = 0; e < 16; ++e) {
        unsigned int a1 = u1[e], a2 = u2v[e];
#pragma unroll
        for (int off = 1; off < 16; off <<= 1) {
            unsigned int b1 = (unsigned int)__shfl_xor((int)a1, off);
            unsigned int b2 = (unsigned int)__shfl_xor((int)a2, off);
            unsigned int m1 = umin_(a1, b1);
            a2 = umin_(umax_(a1, b1), umin_(a2, b2));
            a1 = m1;
        }
        u1[e] = a1; u2v[e] = a2;
    }

    if (lr == 0) {
        int cand = q * 2 + wn;
#pragma unroll
        for (int i = 0; i < 4; ++i)
#pragma unroll
            for (int r = 0; r < 4; ++r) {
                int m = m0 + wm * 64 + i * 16 + lk * 4 + r;
                out2[(size_t)cand * M_ + m] = make_uint2(u1[i * 4 + r], u2v[i * 4 + r]);
            }
    }
}

// ---------------------------------------------------------------------------
// combine 8 candidate streams -> global packed top-2 per row
// ---------------------------------------------------------------------------
__global__ __launch_bounds__(256) void combine8_kernel(
    const uint2* __restrict__ out2, uint2* __restrict__ hard2)
{
    int m = blockIdx.x * 256 + threadIdx.x;
    uint2 g = out2[m];
#pragma unroll
    for (int c = 1; c < 8; ++c) {
        uint2 o = out2[(size_t)c * M_ + m];
        unsigned int m1 = umin_(g.x, o.x);
        g.y = umin_(umax_(g.x, o.x), umin_(g.y, o.y));
        g.x = m1;
    }
    hard2[m] = g;
}

// ---------------------------------------------------------------------------
// fused exact rescore + loss. Exact fp32 student-distance of both candidates
// picks the index (teacher-code masked, tie -> smaller k); d_neg from teacher.
// ---------------------------------------------------------------------------
__global__ __launch_bounds__(256) void loss_kernel(
    const float* __restrict__ student, const float* __restrict__ teacher,
    const float* __restrict__ cb, const uint2* __restrict__ hard2,
    const int* __restrict__ codes, float* __restrict__ partials)
{
    const int m = blockIdx.x * 256 + threadIdx.x;
    const int b = m / T_;
    const int t = m % T_;
    uint2 h = hard2[m];
    const int k1 = (int)(h.x & 0xFFFu);
    const int k2 = (int)(h.y & 0xFFFu);
    const int tc = codes[m];

    const float* sp = student + (size_t)b * C_ * T_ + t;
    const float* tp = teacher + (size_t)b * C_ * T_ + t;
    const float4* c1p = reinterpret_cast<const float4*>(cb + (size_t)k1 * C_);
    const float4* c2p = reinterpret_cast<const float4*>(cb + (size_t)k2 * C_);

    float dp = 0.f, ds1 = 0.f, ds2 = 0.f, dt1 = 0.f, dt2 = 0.f;
    for (int c4 = 0; c4 < C_ / 4; ++c4) {
        float4 cv1 = c1p[c4];
        float4 cv2 = c2p[c4];
        float a0 = tp[(size_t)(c4 * 4 + 0) * T_];
        float a1 = tp[(size_t)(c4 * 4 + 1) * T_];
        float a2 = tp[(size_t)(c4 * 4 + 2) * T_];
        float a3 = tp[(size_t)(c4 * 4 + 3) * T_];
        float p0 = sp[(size_t)(c4 * 4 + 0) * T_];
        float p1 = sp[(size_t)(c4 * 4 + 1) * T_];
        float p2 = sp[(size_t)(c4 * 4 + 2) * T_];
        float p3 = sp[(size_t)(c4 * 4 + 3) * T_];
        float e;
        e = a0 - p0;   dp  = fmaf(e, e, dp);
        e = a1 - p1;   dp  = fmaf(e, e, dp);
        e = a2 - p2;   dp  = fmaf(e, e, dp);
        e = a3 - p3;   dp  = fmaf(e, e, dp);
        e = p0 - cv1.x; ds1 = fmaf(e, e, ds1);
        e = p1 - cv1.y; ds1 = fmaf(e, e, ds1);
        e = p2 - cv1.z; ds1 = fmaf(e, e, ds1);
        e = p3 - cv1.w; ds1 = fmaf(e, e, ds1);
        e = p0 - cv2.x; ds2 = fmaf(e, e, ds2);
        e = p1 - cv2.y; ds2 = fmaf(e, e, ds2);
        e = p2 - cv2.z; ds2 = fmaf(e, e, ds2);
        e = p3 - cv2.w; ds2 = fmaf(e, e, ds2);
        e = a0 - cv1.x; dt1 = fmaf(e, e, dt1);
        e = a1 - cv1.y; dt1 = fmaf(e, e, dt1);
        e = a2 - cv1.z; dt1 = fmaf(e, e, dt1);
        e = a3 - cv1.w; dt1 = fmaf(e, e, dt1);
        e = a0 - cv2.x; dt2 = fmaf(e, e, dt2);
        e = a1 - cv2.y; dt2 = fmaf(e, e, dt2);
        e = a2 - cv2.z; dt2 = fmaf(e, e, dt2);
        e = a3 - cv2.w; dt2 = fmaf(e, e, dt2);
    }

    bool v1 = (k1 != tc), v2 = (k2 != tc);
    bool take2;
    if (!v1)      take2 = true;
    else if (!v2) take2 = false;
    else          take2 = (ds2 < ds1) || (ds2 == ds1 && k2 < k1);
    float dn = take2 ? dt2 : dt1;

    float dpos = sqrtf(dp);
    float dneg = sqrtf(dn);
    float loss = fmaxf(dpos - dneg + MARGIN_, 0.f);
    float ind  = (dneg > dpos + MARGIN_) ? 1.f : 0.f;

    __shared__ float sh[4][4];
    float v0 = loss, vv1 = dpos, vv2 = dneg, vv3 = ind;
#pragma unroll
    for (int off = 32; off; off >>= 1) {
        v0  += __shfl_down(v0, off);
        vv1 += __shfl_down(vv1, off);
        vv2 += __shfl_down(vv2, off);
        vv3 += __shfl_down(vv3, off);
    }
    int w = threadIdx.x >> 6, lane = threadIdx.x & 63;
    if (lane == 0) { sh[w][0] = v0; sh[w][1] = vv1; sh[w][2] = vv2; sh[w][3] = vv3; }
    __syncthreads();
    if (threadIdx.x == 0) {
        float s0 = 0, s1 = 0, s2 = 0, s3 = 0;
#pragma unroll
        for (int ww = 0; ww < 4; ++ww) {
            s0 += sh[ww][0]; s1 += sh[ww][1]; s2 += sh[ww][2]; s3 += sh[ww][3];
        }
        partials[blockIdx.x * 4 + 0] = s0;
        partials[blockIdx.x * 4 + 1] = s1;
        partials[blockIdx.x * 4 + 2] = s2;
        partials[blockIdx.x * 4 + 3] = s3;
    }
}

// ---------------------------------------------------------------------------
// final deterministic reduction of 128 partial rows -> 4 means.
// ---------------------------------------------------------------------------
__global__ __launch_bounds__(128) void final_kernel(
    const float* __restrict__ partials, float* __restrict__ out)
{
    __shared__ float sh[2][4];
    int tid = threadIdx.x;
    float s0 = partials[tid * 4 + 0];
    float s1 = partials[tid * 4 + 1];
    float s2 = partials[tid * 4 + 2];
    float s3 = partials[tid * 4 + 3];
#pragma unroll
    for (int off = 32; off; off >>= 1) {
        s0 += __shfl_down(s0, off);
        s1 += __shfl_down(s1, off);
        s2 += __shfl_down(s2, off);
        s3 += __shfl_down(s3, off);
    }
    int w = tid >> 6, lane = tid & 63;
    if (lane == 0) { sh[w][0] = s0; sh[w][1] = s1; sh[w][2] = s2; sh[w][3] = s3; }
    __syncthreads();
    if (tid == 0) {
        const float inv = 1.0f / (float)M_;
        out[0] = (sh[0][0] + sh[1][0]) * inv;
        out[1] = (sh[0][1] + sh[1][1]) * inv;
        out[2] = (sh[0][2] + sh[1][2]) * inv;
        out[3] = (sh[0][3] + sh[1][3]) * inv;
    }
}

// ===========================================================================
extern "C" void kernel_launch(void* const* d_in, const int* in_sizes, int n_in,
                              void* d_out, int out_size, void* d_ws, size_t ws_size,
                              hipStream_t stream)
{
    (void)in_sizes; (void)n_in; (void)out_size; (void)ws_size;
    const float* student = (const float*)d_in[0];
    const float* teacher = (const float*)d_in[1];
    const float* cb      = (const float*)d_in[2];
    const int*   codes   = (const int*)d_in[3];
    float* out = (float*)d_out;
    char* ws = (char*)d_ws;

    // ws layout (~39 MB)
    const size_t OFF_APACK = 0;                        // 32 MB (M x 512 u16)
    const size_t OFF_BPACK = (size_t)M_ * 512 * 2;     //  4 MB (K x 512 u16)
    const size_t OFF_CBN   = OFF_BPACK + (size_t)K_ * 512 * 2;   // 16 KB
    const size_t OFF_OUT2  = OFF_CBN + K_ * 4;         //  2 MB (8 x M uint2)
    const size_t OFF_HARD  = OFF_OUT2 + (size_t)8 * M_ * 8;      // 256 KB
    const size_t OFF_PARTS = OFF_HARD + (size_t)M_ * 8;          // 2 KB

    unsigned short* Apack = (unsigned short*)(ws + OFF_APACK);
    unsigned short* Bpack = (unsigned short*)(ws + OFF_BPACK);
    float* cbnb  = (float*)(ws + OFF_CBN);
    uint2* out2  = (uint2*)(ws + OFF_OUT2);
    uint2* hard2 = (uint2*)(ws + OFF_HARD);
    float* parts = (float*)(ws + OFF_PARTS);

    packA_kernel<<<dim3(T_ / 64, C_ / 64, B_), 256, 0, stream>>>(student, Apack);
    packB_norm_kernel<<<K_ / 4, 256, 0, stream>>>(cb, Bpack, cbnb);
    screen_kernel<<<dim3(M_ / 128, 4), 256, 0, stream>>>(Apack, Bpack, cbnb, out2);
    combine8_kernel<<<M_ / 256, 256, 0, stream>>>(out2, hard2);
    loss_kernel<<<M_ / 256, 256, 0, stream>>>(student, teacher, cb, hard2, codes, parts);
    final_kernel<<<1, 128, 0, stream>>>(parts, out);
}